// Round 8
// baseline (122.018 us; speedup 1.0000x reference)
//
#include <hip/hip_runtime.h>
#include <math.h>

// ws footprint: 50,331,648 bytes (decay table lives in the free region).
#define B_  2
#define T_  2048
#define C_  1024
#define NH_ 16
#define HD_ 64
#define N3_ 3072

typedef float f32x4 __attribute__((ext_vector_type(4)));
typedef short bf16x8 __attribute__((ext_vector_type(8)));
typedef unsigned short u16;
typedef float f32x4_base __attribute__((ext_vector_type(4)));
typedef f32x4_base __attribute__((aligned(4))) f32x4u;   // 4B-aligned vector load

// Q prescale: 1/sqrt(64) * log2(e), so softmax uses exp2 directly.
#define QSCALE 0.18033688011112042f

#if __has_builtin(__builtin_amdgcn_exp2f)
#define EXP2(x) __builtin_amdgcn_exp2f(x)
#else
#define EXP2(x) exp2f(x)
#endif

__device__ __forceinline__ u16 f2bf(float x) {
  unsigned int u = __builtin_bit_cast(unsigned int, x);
  u += 0x7FFFu + ((u >> 16) & 1u);
  return (u16)(u >> 16);
}

__device__ __forceinline__ unsigned int cvt_pk_bf16(float lo, float hi) {
  unsigned int r;
  asm("v_cvt_pk_bf16_f32 %0, %1, %2" : "=v"(r) : "v"(lo), "v"(hi));
  return r;
}

#define GLD16(g, l) __builtin_amdgcn_global_load_lds( \
    (__attribute__((address_space(1))) void*)(g), \
    (__attribute__((address_space(3))) void*)(l), 16, 0, 0)

// ---------------- converts ----------------
__global__ __launch_bounds__(256) void cvt4_kernel(const float* __restrict__ in,
                                                   u16* __restrict__ out, int n) {
  int i = (blockIdx.x * 256 + threadIdx.x) * 4;
  if (i >= n) return;
  float4 v = *(const float4*)(in + i);
  ushort4 o;
  o.x = f2bf(v.x); o.y = f2bf(v.y); o.z = f2bf(v.z); o.w = f2bf(v.w);
  *(ushort4*)(out + i) = o;
}

// out[c][r] = bf16(in[r][c]); R,Cc multiples of 32
__global__ __launch_bounds__(256) void transpose_cvt_kernel(const float* __restrict__ in,
                                                            u16* __restrict__ out,
                                                            int R, int Cc) {
  __shared__ float tile[32][33];
  int c0 = blockIdx.x * 32, r0 = blockIdx.y * 32;
  int tx = threadIdx.x & 31, ty = threadIdx.x >> 5;
#pragma unroll
  for (int rr = ty; rr < 32; rr += 8)
    tile[rr][tx] = in[(size_t)(r0 + rr) * Cc + c0 + tx];
  __syncthreads();
#pragma unroll
  for (int rr = ty; rr < 32; rr += 8)
    out[(size_t)(c0 + rr) * R + r0 + tx] = f2bf(tile[tx][rr]);
}

// Reversed + padded decay table: decR[j] = decay(2047-j) for j<=2047, 1.0 above
// (pad entries are only ever multiplied by p==0 in the masked region).
__global__ __launch_bounds__(256) void decay_init_kernel(float* __restrict__ decR) {
  int j = blockIdx.x * 256 + threadIdx.x;
  if (j >= 2176) return;
  int d = 2047 - j;
  float v = 1.0f;
  if (d >= 15) v = 1.0f - powf((float)(d - 15) * (1.0f / 2032.0f), 0.36787944117144233f);
  decR[j] = v;   // d < 15 (incl. negative pad) -> 1.0
}

// ---------------- GEMM: C[M][N] = A[M][K] * Bt[N][K]^T ----------------
// 128x128 tile, 4 waves, BK=32, double-buffered LDS, 1 barrier/iter.
// Flattened grid with bijective XCD-chunk swizzle (grid %8 == 0).
// MODE 0: Q,K bf16 into qkb [which][bh][t][d] (Q prescaled);
//         V written TRANSPOSED into VT [bh][d][t] (ushort4 over 4 consecutive t).
// MODE 1: fp32 row-major.
template<int MODE>
__global__ __launch_bounds__(256, 3) void gemm128_kernel(
    const u16* __restrict__ A, const u16* __restrict__ Bt,
    float* __restrict__ Cf, u16* __restrict__ Cq, u16* __restrict__ Vt,
    int M, int N, int K)
{
  __shared__ char lds[32768];
  const int lane = threadIdx.x & 63;
  const int wave = threadIdx.x >> 6;
  const int nxb = N >> 7;
  const int orig = blockIdx.x;
  const int cpx = (int)gridDim.x >> 3;
  const int wg = (orig & 7) * cpx + (orig >> 3);
  const int m0 = (wg / nxb) << 7;
  const int n0 = (wg % nxb) << 7;
  const int wm = wave >> 1, wn = wave & 1;

  f32x4 acc[4][4] = {};

#define GSTAGE(buf, k0)                                                          \
  {                                                                              \
    _Pragma("unroll")                                                            \
    for (int c = 0; c < 2; ++c) {                                                \
      int chunk = wave * 2048 + c * 1024;                                        \
      int row = (chunk >> 6) + (lane >> 2);                                      \
      int wb = ((lane & 3) << 4) ^ ((row & 3) << 4);                             \
      GLD16((const char*)(A  + (size_t)(m0 + row) * K + (k0)) + wb,              \
            lds + (buf) * 16384 + chunk);                                        \
      GLD16((const char*)(Bt + (size_t)(n0 + row) * K + (k0)) + wb,              \
            lds + (buf) * 16384 + 8192 + chunk);                                 \
    }                                                                            \
  }

  GSTAGE(0, 0);
  __syncthreads();

  for (int k0 = 0; k0 < K; k0 += 32) {
    const int cur = (k0 >> 5) & 1;
    if (k0 + 32 < K) GSTAGE(cur ^ 1, k0 + 32);
    const char* base = lds + cur * 16384;
    bf16x8 af[4], bfr[4];
#pragma unroll
    for (int m = 0; m < 4; ++m) {
      int row = wm * 64 + m * 16 + (lane & 15);
      int wb = ((lane >> 4) << 4) ^ ((row & 3) << 4);
      af[m] = *(const bf16x8*)(base + row * 64 + wb);
    }
#pragma unroll
    for (int n = 0; n < 4; ++n) {
      int row = wn * 64 + n * 16 + (lane & 15);
      int wb = ((lane >> 4) << 4) ^ ((row & 3) << 4);
      bfr[n] = *(const bf16x8*)(base + 8192 + row * 64 + wb);
    }
    __builtin_amdgcn_s_setprio(1);
#pragma unroll
    for (int m = 0; m < 4; ++m)
#pragma unroll
      for (int n = 0; n < 4; ++n)
        acc[m][n] = __builtin_amdgcn_mfma_f32_16x16x32_bf16(af[m], bfr[n], acc[m][n], 0, 0, 0);
    __builtin_amdgcn_s_setprio(0);
    __syncthreads();
  }

#pragma unroll
  for (int m = 0; m < 4; ++m) {
    int grow0 = m0 + wm * 64 + m * 16 + ((lane >> 4) << 2);
#pragma unroll
    for (int n = 0; n < 4; ++n) {
      int gcol = n0 + wn * 64 + n * 16 + (lane & 15);
      f32x4 v = acc[m][n];
      if (MODE == 0) {
        int bb = grow0 >> 11, tt0 = grow0 & 2047;
        int which = gcol >> 10, rem = gcol & 1023;
        int hh = rem >> 6, dd = rem & 63;
        if (which < 2) {
#pragma unroll
          for (int r = 0; r < 4; ++r) {
            float ov = (which == 0) ? v[r] * QSCALE : v[r];
            Cq[((size_t)(which * 32 + bb * 16 + hh) * 2048 + tt0 + r) * 64 + dd] = f2bf(ov);
          }
        } else {
          ushort4 o;
          o.x = f2bf(v[0]); o.y = f2bf(v[1]); o.z = f2bf(v[2]); o.w = f2bf(v[3]);
          *(ushort4*)(Vt + ((size_t)(bb * 16 + hh) * 64 + dd) * 2048 + tt0) = o;
        }
      } else {
#pragma unroll
        for (int r = 0; r < 4; ++r)
          Cf[(size_t)(grow0 + r) * N + gcol] = v[r];
      }
    }
  }
#undef GSTAGE
}

// ---------------- fused flash attention with post-softmax decay ----------------
// flat grid 512; block = one 128-row q-tile (two 64-row groups g=0,1), 4 waves;
// each wave owns 16 rows of EACH group -> kf/vf LDS reads amortize over 32 q.
// Stage-iters per bh: 272 (vs 528 for 64-row tiles) -- the per-CU per-iter cost
// (~400cyc barrier+stage bundle) was the R5-R7 wall, invariant to width.
// tile t -> qt = (t<8 ? t : 23-t): CU-mates (stride-256, tile+8) sum to 36 iters.
// S^T = mfma(K,Q): col=q=lane&15, row=key=quad*4+r -> keys lane-local.
__global__ __launch_bounds__(256, 3) void attn_kernel(
    const u16* __restrict__ qkb, const u16* __restrict__ vtg,
    const float* __restrict__ decR, u16* __restrict__ yb)
{
  __shared__ char klds[2][8192];   // K tile [64 keys][128B], XOR-swizzled
  __shared__ char vlds[2][8192];   // V^T tile [64 d][128B keys], XOR-swizzled
  __shared__ u16 plds[128 * 72];   // P [q][key] bf16, stride 72 (16B-aligned rows)

  const int lane = threadIdx.x & 63;
  const int wave = threadIdx.x >> 6;
  const int quad = lane >> 4;
  const int l15 = lane & 15;
  const int orig = blockIdx.x;
  const int xcd = orig & 7;
  const int s6 = orig >> 3;            // 0..63 within XCD
  const int bh = (xcd << 2) + (s6 & 3);
  const int tile = s6 >> 2;            // 0..15
  const int qt = tile < 8 ? tile : 23 - tile;
  const int b = bh >> 4, h = bh & 15;

  const u16* Q   = qkb + (size_t)bh * T_ * HD_;
  const u16* Kg  = qkb + (size_t)(32 + bh) * T_ * HD_;
  const u16* VTg = vtg + (size_t)bh * HD_ * T_;

  const int wrow0 = qt * 128 + wave * 16;   // group 0 rows; group 1 = +64
  const int q0 = wrow0 + l15;
  const int q1 = q0 + 64;
  const int rb0 = 2047 - q0 + quad * 4;     // reversed-decay base, group 0
  const int rb1 = rb0 - 64;
  const int prow0 = wave * 16 + l15;        // plds row, group 0; group 1 = +64

  bf16x8 qa[2][2];
#pragma unroll
  for (int g = 0; g < 2; ++g) {
    const u16* qp = Q + (size_t)(q0 + g * 64) * HD_ + quad * 8;
    qa[g][0] = *(const bf16x8*)qp;
    qa[g][1] = *(const bf16x8*)(qp + 32);
  }

  f32x4 acc[2][4] = {};
  float lsum[2] = {0.0f, 0.0f};

#define ASTAGE(buf, kt)                                                          \
  {                                                                              \
    _Pragma("unroll")                                                            \
    for (int c = 0; c < 2; ++c) {                                                \
      int chunk = wave * 2048 + c * 1024;                                        \
      int row = (chunk >> 7) + (lane >> 3);                                      \
      int wb = ((lane & 7) << 4) ^ ((row & 7) << 4);                             \
      GLD16((const char*)(Kg + (size_t)((kt) * 64 + row) * HD_) + wb,            \
            klds[buf] + chunk);                                                  \
      GLD16((const char*)(VTg + (size_t)row * T_ + (kt) * 64) + wb,              \
            vlds[buf] + chunk);                                                  \
    }                                                                            \
  }

  ASTAGE(0, 0);
  __syncthreads();

  const int nkt = 2 * qt + 2;
  for (int kt = 0; kt < nkt; ++kt) {
    const int cur = kt & 1;
    if (kt + 1 < nkt) ASTAGE(cur ^ 1, kt + 1);
    const bool act0 = (kt <= 2 * qt);   // group 0 fully masked in last iter

    // K fragments (read once, serve both 16-row groups = 32 q-rows)
    bf16x8 kf[4][2];
#pragma unroll
    for (int f = 0; f < 4; ++f) {
      int krow = f * 16 + l15;
      int base = krow * 128;
      int msk = (krow & 7) << 4;
      kf[f][0] = *(const bf16x8*)(klds[cur] + base + ((quad * 16) ^ msk));
      kf[f][1] = *(const bf16x8*)(klds[cur] + base + ((64 + quad * 16) ^ msk));
    }

    // decay factors: one dwordx4 per f-block from the reversed table (L1-hot)
    f32x4 d0[4], d1[4];
    const float* dR1 = decR + (rb1 + kt * 64);
#pragma unroll
    for (int f = 0; f < 4; ++f) d1[f] = *(const f32x4u*)(dR1 + f * 16);
    if (act0) {
      const float* dR0 = decR + (rb0 + kt * 64);
#pragma unroll
      for (int f = 0; f < 4; ++f) d0[f] = *(const f32x4u*)(dR0 + f * 16);
    }

    // S^T = K Q^T (log2 domain): col=q=l15, row=key=f*16+quad*4+r
    f32x4 s0[4], s1[4];
    __builtin_amdgcn_s_setprio(1);
#pragma unroll
    for (int f = 0; f < 4; ++f) {
      f32x4 t = {};
      t = __builtin_amdgcn_mfma_f32_16x16x32_bf16(kf[f][0], qa[1][0], t, 0, 0, 0);
      t = __builtin_amdgcn_mfma_f32_16x16x32_bf16(kf[f][1], qa[1][1], t, 0, 0, 0);
      s1[f] = t;
    }
    if (act0) {
#pragma unroll
      for (int f = 0; f < 4; ++f) {
        f32x4 t = {};
        t = __builtin_amdgcn_mfma_f32_16x16x32_bf16(kf[f][0], qa[0][0], t, 0, 0, 0);
        t = __builtin_amdgcn_mfma_f32_16x16x32_bf16(kf[f][1], qa[0][1], t, 0, 0, 0);
        s0[f] = t;
      }
    }
    __builtin_amdgcn_s_setprio(0);

    if (kt == 2 * qt) {        // diagonal tile for group 0
#pragma unroll
      for (int f = 0; f < 4; ++f) {
        int key0 = kt * 64 + f * 16 + quad * 4;
#pragma unroll
        for (int r = 0; r < 4; ++r)
          if (key0 + r > q0) s0[f][r] = -1e30f;
      }
    }
    if (kt == 2 * qt + 1) {    // diagonal tile for group 1
#pragma unroll
      for (int f = 0; f < 4; ++f) {
        int key0 = kt * 64 + f * 16 + quad * 4;
#pragma unroll
        for (int r = 0; r < 4; ++r)
          if (key0 + r > q1) s1[f][r] = -1e30f;
      }
    }

    // softmax: denom = sum exp2(s); numerator = exp2(s)*decay -> packed bf16
#pragma unroll
    for (int f = 0; f < 4; ++f) {
      f32x4 p;
#pragma unroll
      for (int r = 0; r < 4; ++r) p[r] = EXP2(s1[f][r]);
      lsum[1] += (p[0] + p[1]) + (p[2] + p[3]);
      unsigned int w0 = cvt_pk_bf16(p[0] * d1[f][0], p[1] * d1[f][1]);
      unsigned int w1 = cvt_pk_bf16(p[2] * d1[f][2], p[3] * d1[f][3]);
      uint2 wv; wv.x = w0; wv.y = w1;
      *(uint2*)(plds + (size_t)(64 + prow0) * 72 + f * 16 + quad * 4) = wv;
    }
    if (act0) {
#pragma unroll
      for (int f = 0; f < 4; ++f) {
        f32x4 p;
#pragma unroll
        for (int r = 0; r < 4; ++r) p[r] = EXP2(s0[f][r]);
        lsum[0] += (p[0] + p[1]) + (p[2] + p[3]);
        unsigned int w0 = cvt_pk_bf16(p[0] * d0[f][0], p[1] * d0[f][1]);
        unsigned int w1 = cvt_pk_bf16(p[2] * d0[f][2], p[3] * d0[f][3]);
        uint2 wv; wv.x = w0; wv.y = w1;
        *(uint2*)(plds + (size_t)prow0 * 72 + f * 16 + quad * 4) = wv;
      }
    }

    // V fragments (read once, serve both groups)
    bf16x8 vf[4][2];
#pragma unroll
    for (int n = 0; n < 4; ++n) {
      int vrow = n * 16 + l15;
      int mskv = (vrow & 7) << 4;
#pragma unroll
      for (int ks = 0; ks < 2; ++ks)
        vf[n][ks] = *(const bf16x8*)(vlds[cur] + vrow * 128 + ((ks * 64 + quad * 16) ^ mskv));
    }

    // y += P @ V (plds rows are wave-private; same-wave ds order suffices)
    __builtin_amdgcn_s_setprio(1);
#pragma unroll
    for (int ks = 0; ks < 2; ++ks) {
      bf16x8 pa = *(const bf16x8*)(plds + (size_t)(64 + prow0) * 72 + ks * 32 + quad * 8);
#pragma unroll
      for (int n = 0; n < 4; ++n)
        acc[1][n] = __builtin_amdgcn_mfma_f32_16x16x32_bf16(pa, vf[n][ks], acc[1][n], 0, 0, 0);
    }
    if (act0) {
#pragma unroll
      for (int ks = 0; ks < 2; ++ks) {
        bf16x8 pa = *(const bf16x8*)(plds + (size_t)prow0 * 72 + ks * 32 + quad * 8);
#pragma unroll
        for (int n = 0; n < 4; ++n)
          acc[0][n] = __builtin_amdgcn_mfma_f32_16x16x32_bf16(pa, vf[n][ks], acc[0][n], 0, 0, 0);
      }
    }
    __builtin_amdgcn_s_setprio(0);
    __syncthreads();   // drains vmcnt(0): next buffer staged, everyone done with cur
  }
#undef ASTAGE

  // finalize: per group, denom for q=l15 -> reduce across quads, broadcast
#pragma unroll
  for (int g = 0; g < 2; ++g) {
    float lv = lsum[g];
    lv += __shfl_xor(lv, 16);
    lv += __shfl_xor(lv, 32);
    float rb[4];
#pragma unroll
    for (int r = 0; r < 4; ++r)
      rb[r] = 1.0f / __shfl(lv, quad * 4 + r, 16);
#pragma unroll
    for (int n = 0; n < 4; ++n) {
      int d = h * 64 + n * 16 + l15;
#pragma unroll
      for (int r = 0; r < 4; ++r) {
        int t = wrow0 + g * 64 + quad * 4 + r;
        yb[((size_t)b * T_ + t) * 1024 + d] = f2bf(acc[g][n][r] * rb[r]);
      }
    }
  }
}

// ---------------- launch ----------------
extern "C" void kernel_launch(void* const* d_in, const int* in_sizes, int n_in,
                              void* d_out, int out_size, void* d_ws, size_t ws_size,
                              hipStream_t stream) {
  const float* x  = (const float*)d_in[0];
  const float* Wa = (const float*)d_in[1];
  const float* Wp = (const float*)d_in[2];
  float* out = (float*)d_out;
  char* ws = (char*)d_ws;

  // workspace layout (bytes), total 50,331,648
  u16*   xb    = (u16*)(ws + 0);           //  8,388,608  x bf16; reused as yb
  u16*   WaT   = (u16*)(ws + 8388608);     //  6,291,456  W_attn^T bf16
  u16*   WpT   = (u16*)(ws + 14680064);    //  2,097,152  W_proj^T bf16
  u16*   qkb   = (u16*)(ws + 16777216);    // 16,777,216  Q,K bf16 [2][32][2048][64]
  float* decR  = (float*)(ws + 33554432);  //      8,704  reversed padded decay table
  u16*   VT    = (u16*)(ws + 41943040);    //  8,388,608  V^T bf16 [32][64][2048]
  u16*   yb    = xb;

  decay_init_kernel<<<9, 256, 0, stream>>>(decR);
  cvt4_kernel<<<4096, 256, 0, stream>>>(x, xb, B_ * T_ * C_);
  transpose_cvt_kernel<<<dim3(96, 32), 256, 0, stream>>>(Wa, WaT, C_, N3_);
  transpose_cvt_kernel<<<dim3(32, 32), 256, 0, stream>>>(Wp, WpT, C_, C_);

  gemm128_kernel<0><<<768, 256, 0, stream>>>(
      xb, WaT, nullptr, qkb, VT, B_ * T_, N3_, C_);
  attn_kernel<<<512, 256, 0, stream>>>(qkb, VT, decR, yb);
  gemm128_kernel<1><<<256, 256, 0, stream>>>(
      yb, WpT, out, nullptr, nullptr, B_ * T_, 1024, 1024);
}

// Round 9
// 114.076 us; speedup vs baseline: 1.0696x; 1.0696x over previous
//
#include <hip/hip_runtime.h>
#include <math.h>

// ws footprint: 50,331,648 bytes (decay table lives in the free region).
#define B_  2
#define T_  2048
#define C_  1024
#define NH_ 16
#define HD_ 64
#define N3_ 3072

typedef float f32x4 __attribute__((ext_vector_type(4)));
typedef short bf16x8 __attribute__((ext_vector_type(8)));
typedef unsigned short u16;
typedef float f32x4_base __attribute__((ext_vector_type(4)));
typedef f32x4_base __attribute__((aligned(4))) f32x4u;   // 4B-aligned vector load

// Q prescale: 1/sqrt(64) * log2(e), so softmax uses exp2 directly.
#define QSCALE 0.18033688011112042f

#if __has_builtin(__builtin_amdgcn_exp2f)
#define EXP2(x) __builtin_amdgcn_exp2f(x)
#else
#define EXP2(x) exp2f(x)
#endif

__device__ __forceinline__ u16 f2bf(float x) {
  unsigned int u = __builtin_bit_cast(unsigned int, x);
  u += 0x7FFFu + ((u >> 16) & 1u);
  return (u16)(u >> 16);
}

__device__ __forceinline__ unsigned int cvt_pk_bf16(float lo, float hi) {
  unsigned int r;
  asm("v_cvt_pk_bf16_f32 %0, %1, %2" : "=v"(r) : "v"(lo), "v"(hi));
  return r;
}

#define GLD16(g, l) __builtin_amdgcn_global_load_lds( \
    (__attribute__((address_space(1))) void*)(g), \
    (__attribute__((address_space(3))) void*)(l), 16, 0, 0)

// ---------------- converts ----------------
__global__ __launch_bounds__(256) void cvt4_kernel(const float* __restrict__ in,
                                                   u16* __restrict__ out, int n) {
  int i = (blockIdx.x * 256 + threadIdx.x) * 4;
  if (i >= n) return;
  float4 v = *(const float4*)(in + i);
  ushort4 o;
  o.x = f2bf(v.x); o.y = f2bf(v.y); o.z = f2bf(v.z); o.w = f2bf(v.w);
  *(ushort4*)(out + i) = o;
}

// out[c][r] = bf16(in[r][c]); R,Cc multiples of 32
__global__ __launch_bounds__(256) void transpose_cvt_kernel(const float* __restrict__ in,
                                                            u16* __restrict__ out,
                                                            int R, int Cc) {
  __shared__ float tile[32][33];
  int c0 = blockIdx.x * 32, r0 = blockIdx.y * 32;
  int tx = threadIdx.x & 31, ty = threadIdx.x >> 5;
#pragma unroll
  for (int rr = ty; rr < 32; rr += 8)
    tile[rr][tx] = in[(size_t)(r0 + rr) * Cc + c0 + tx];
  __syncthreads();
#pragma unroll
  for (int rr = ty; rr < 32; rr += 8)
    out[(size_t)(c0 + rr) * R + r0 + tx] = f2bf(tile[tx][rr]);
}

// Reversed + padded decay table: decR[j] = decay(2047-j) for j<=2047, 1.0 above
// (pad entries are only ever multiplied by p==0 in the masked region).
__global__ __launch_bounds__(256) void decay_init_kernel(float* __restrict__ decR) {
  int j = blockIdx.x * 256 + threadIdx.x;
  if (j >= 2176) return;
  int d = 2047 - j;
  float v = 1.0f;
  if (d >= 15) v = 1.0f - powf((float)(d - 15) * (1.0f / 2032.0f), 0.36787944117144233f);
  decR[j] = v;   // d < 15 (incl. negative pad) -> 1.0
}

// ---------------- GEMM: C[M][N] = A[M][K] * Bt[N][K]^T ----------------
// 128x128 tile, 4 waves, BK=32, double-buffered LDS, 1 barrier/iter.
// Flattened grid with bijective XCD-chunk swizzle (grid %8 == 0).
// MODE 0: Q,K bf16 into qkb [which][bh][t][d] (Q prescaled);
//         V written TRANSPOSED into VT [bh][d][t] (ushort4 over 4 consecutive t).
// MODE 1: fp32 row-major.
template<int MODE>
__global__ __launch_bounds__(256, 3) void gemm128_kernel(
    const u16* __restrict__ A, const u16* __restrict__ Bt,
    float* __restrict__ Cf, u16* __restrict__ Cq, u16* __restrict__ Vt,
    int M, int N, int K)
{
  __shared__ char lds[32768];
  const int lane = threadIdx.x & 63;
  const int wave = threadIdx.x >> 6;
  const int nxb = N >> 7;
  const int orig = blockIdx.x;
  const int cpx = (int)gridDim.x >> 3;
  const int wg = (orig & 7) * cpx + (orig >> 3);
  const int m0 = (wg / nxb) << 7;
  const int n0 = (wg % nxb) << 7;
  const int wm = wave >> 1, wn = wave & 1;

  f32x4 acc[4][4] = {};

#define GSTAGE(buf, k0)                                                          \
  {                                                                              \
    _Pragma("unroll")                                                            \
    for (int c = 0; c < 2; ++c) {                                                \
      int chunk = wave * 2048 + c * 1024;                                        \
      int row = (chunk >> 6) + (lane >> 2);                                      \
      int wb = ((lane & 3) << 4) ^ ((row & 3) << 4);                             \
      GLD16((const char*)(A  + (size_t)(m0 + row) * K + (k0)) + wb,              \
            lds + (buf) * 16384 + chunk);                                        \
      GLD16((const char*)(Bt + (size_t)(n0 + row) * K + (k0)) + wb,              \
            lds + (buf) * 16384 + 8192 + chunk);                                 \
    }                                                                            \
  }

  GSTAGE(0, 0);
  __syncthreads();

  for (int k0 = 0; k0 < K; k0 += 32) {
    const int cur = (k0 >> 5) & 1;
    if (k0 + 32 < K) GSTAGE(cur ^ 1, k0 + 32);
    const char* base = lds + cur * 16384;
    bf16x8 af[4], bfr[4];
#pragma unroll
    for (int m = 0; m < 4; ++m) {
      int row = wm * 64 + m * 16 + (lane & 15);
      int wb = ((lane >> 4) << 4) ^ ((row & 3) << 4);
      af[m] = *(const bf16x8*)(base + row * 64 + wb);
    }
#pragma unroll
    for (int n = 0; n < 4; ++n) {
      int row = wn * 64 + n * 16 + (lane & 15);
      int wb = ((lane >> 4) << 4) ^ ((row & 3) << 4);
      bfr[n] = *(const bf16x8*)(base + 8192 + row * 64 + wb);
    }
    __builtin_amdgcn_s_setprio(1);
#pragma unroll
    for (int m = 0; m < 4; ++m)
#pragma unroll
      for (int n = 0; n < 4; ++n)
        acc[m][n] = __builtin_amdgcn_mfma_f32_16x16x32_bf16(af[m], bfr[n], acc[m][n], 0, 0, 0);
    __builtin_amdgcn_s_setprio(0);
    __syncthreads();
  }

#pragma unroll
  for (int m = 0; m < 4; ++m) {
    int grow0 = m0 + wm * 64 + m * 16 + ((lane >> 4) << 2);
#pragma unroll
    for (int n = 0; n < 4; ++n) {
      int gcol = n0 + wn * 64 + n * 16 + (lane & 15);
      f32x4 v = acc[m][n];
      if (MODE == 0) {
        int bb = grow0 >> 11, tt0 = grow0 & 2047;
        int which = gcol >> 10, rem = gcol & 1023;
        int hh = rem >> 6, dd = rem & 63;
        if (which < 2) {
#pragma unroll
          for (int r = 0; r < 4; ++r) {
            float ov = (which == 0) ? v[r] * QSCALE : v[r];
            Cq[((size_t)(which * 32 + bb * 16 + hh) * 2048 + tt0 + r) * 64 + dd] = f2bf(ov);
          }
        } else {
          ushort4 o;
          o.x = f2bf(v[0]); o.y = f2bf(v[1]); o.z = f2bf(v[2]); o.w = f2bf(v[3]);
          *(ushort4*)(Vt + ((size_t)(bb * 16 + hh) * 64 + dd) * 2048 + tt0) = o;
        }
      } else {
#pragma unroll
        for (int r = 0; r < 4; ++r)
          Cf[(size_t)(grow0 + r) * N + gcol] = v[r];
      }
    }
  }
#undef GSTAGE
}

// ---------------- fused flash attention with post-softmax decay ----------------
// flat grid 1024, one 64-row q-tile per block; 4 waves x 16 rows; LDS 40960.
// Dispatch mapping (the R9 fix): heavy tiles FIRST. g=orig>>5, j3=g>>3 is the
// dispatch class (class 0 = first 256 blocks): qt = (3-j3)*8 + alternate(g&7).
// -> resident CU-mates sum to 62 iters (balanced) AND the queued/backfill blocks
// are the 1-8-iter lightweights, killing the R7/R8 heavy-tail.
// bh = ((orig&7)<<2) + ((orig>>3)&3): all 32 tiles of a head on one XCD.
// S^T = mfma(K,Q): col=q=lane&15, row=key=quad*4+r -> keys lane-local.
__global__ __launch_bounds__(256, 4) void attn_kernel(
    const u16* __restrict__ qkb, const u16* __restrict__ vtg,
    const float* __restrict__ decR, u16* __restrict__ yb)
{
  __shared__ char klds[2][8192];   // K tile [64 keys][128B], XOR-swizzled
  __shared__ char vlds[2][8192];   // V^T tile [64 d][128B keys], XOR-swizzled
  __shared__ char plds[8192];      // P [64 q][64 keys] bf16, XOR-swizzled rows

  const int lane = threadIdx.x & 63;
  const int wave = threadIdx.x >> 6;
  const int quad = lane >> 4;
  const int l15 = lane & 15;
  const int orig = blockIdx.x;
  const int x = orig & 31;
  const int bh = ((x & 7) << 2) + (x >> 3);    // 4 heads per XCD
  const int g = orig >> 5;
  const int j3 = g >> 3;                       // dispatch class, 0 first
  const int g0 = g & 7;
  const int qt = (3 - j3) * 8 + ((j3 & 1) ? (7 - g0) : g0);   // heavy first
  const int b = bh >> 4, h = bh & 15;

  const u16* Q   = qkb + (size_t)bh * T_ * HD_;
  const u16* Kg  = qkb + (size_t)(32 + bh) * T_ * HD_;
  const u16* VTg = vtg + (size_t)bh * HD_ * T_;

  const int wrow = qt * 64 + wave * 16;
  const int q = wrow + l15;            // this lane's S^T column (global q)
  const int rbase0 = 2047 - q + quad * 4;
  const int prow = wave * 16 + l15;    // plds row (this lane's q, local)
  const int pswz = (l15 & 7) << 4;

  bf16x8 qa[2];
  { const u16* qp = Q + (size_t)q * HD_ + quad * 8;
    qa[0] = *(const bf16x8*)qp; qa[1] = *(const bf16x8*)(qp + 32); }

  f32x4 acc[4] = {};
  float lsum = 0.0f;

#define ASTAGE(buf, kt)                                                          \
  {                                                                              \
    _Pragma("unroll")                                                            \
    for (int c = 0; c < 2; ++c) {                                                \
      int chunk = wave * 2048 + c * 1024;                                        \
      int row = (chunk >> 7) + (lane >> 3);                                      \
      int wb = ((lane & 7) << 4) ^ ((row & 7) << 4);                             \
      GLD16((const char*)(Kg + (size_t)((kt) * 64 + row) * HD_) + wb,            \
            klds[buf] + chunk);                                                  \
      GLD16((const char*)(VTg + (size_t)row * T_ + (kt) * 64) + wb,              \
            vlds[buf] + chunk);                                                  \
    }                                                                            \
  }

  ASTAGE(0, 0);
  __syncthreads();

  const int nkt = qt + 1;
  for (int kt = 0; kt < nkt; ++kt) {
    const int cur = kt & 1;
    if (kt + 1 < nkt) ASTAGE(cur ^ 1, kt + 1);

    // K fragments
    bf16x8 kf[4][2];
#pragma unroll
    for (int f = 0; f < 4; ++f) {
      int krow = f * 16 + l15;
      int base = krow * 128;
      int msk = (krow & 7) << 4;
      kf[f][0] = *(const bf16x8*)(klds[cur] + base + ((quad * 16) ^ msk));
      kf[f][1] = *(const bf16x8*)(klds[cur] + base + ((64 + quad * 16) ^ msk));
    }

    // decay factors: one dwordx4 per f-block from the reversed table (L1-hot)
    const float* dR = decR + (rbase0 + kt * 64);
    f32x4 dB[4];
#pragma unroll
    for (int f = 0; f < 4; ++f) dB[f] = *(const f32x4u*)(dR + f * 16);

    // S^T = K Q^T (log2 domain): col=q=l15, row=key=f*16+quad*4+r
    f32x4 s[4];
    __builtin_amdgcn_s_setprio(1);
#pragma unroll
    for (int f = 0; f < 4; ++f) {
      f32x4 t = {};
      t = __builtin_amdgcn_mfma_f32_16x16x32_bf16(kf[f][0], qa[0], t, 0, 0, 0);
      t = __builtin_amdgcn_mfma_f32_16x16x32_bf16(kf[f][1], qa[1], t, 0, 0, 0);
      s[f] = t;
    }
    __builtin_amdgcn_s_setprio(0);

    if (kt == qt) {   // diagonal: mask key > q
#pragma unroll
      for (int f = 0; f < 4; ++f) {
        int key0 = kt * 64 + f * 16 + quad * 4;
#pragma unroll
        for (int r = 0; r < 4; ++r)
          if (key0 + r > q) s[f][r] = -1e30f;
      }
    }

    // softmax: denom = sum exp2(s); numerator = exp2(s)*decay -> packed bf16
#pragma unroll
    for (int f = 0; f < 4; ++f) {
      f32x4 p;
#pragma unroll
      for (int r = 0; r < 4; ++r) p[r] = EXP2(s[f][r]);
      lsum += (p[0] + p[1]) + (p[2] + p[3]);
      unsigned int w0 = cvt_pk_bf16(p[0] * dB[f][0], p[1] * dB[f][1]);
      unsigned int w1 = cvt_pk_bf16(p[2] * dB[f][2], p[3] * dB[f][3]);
      uint2 wv; wv.x = w0; wv.y = w1;
      *(uint2*)(plds + prow * 128 + ((f * 32 + quad * 8) ^ pswz)) = wv;
    }

    // V fragments
    bf16x8 vf[4][2];
#pragma unroll
    for (int n = 0; n < 4; ++n) {
      int vrow = n * 16 + l15;
      int mskv = (vrow & 7) << 4;
#pragma unroll
      for (int ks = 0; ks < 2; ++ks)
        vf[n][ks] = *(const bf16x8*)(vlds[cur] + vrow * 128 + ((ks * 64 + quad * 16) ^ mskv));
    }

    // y += P @ V (plds rows are wave-private; same-wave ds order suffices)
    __builtin_amdgcn_s_setprio(1);
#pragma unroll
    for (int ks = 0; ks < 2; ++ks) {
      bf16x8 pa = *(const bf16x8*)(plds + prow * 128 + ((ks * 64 + quad * 16) ^ pswz));
#pragma unroll
      for (int n = 0; n < 4; ++n)
        acc[n] = __builtin_amdgcn_mfma_f32_16x16x32_bf16(pa, vf[n][ks], acc[n], 0, 0, 0);
    }
    __builtin_amdgcn_s_setprio(0);
    __syncthreads();   // drains vmcnt(0): next buffer staged, everyone done with cur
  }
#undef ASTAGE

  // finalize: denom for q=l15 -> reduce across quads, broadcast to q=quad*4+r
  lsum += __shfl_xor(lsum, 16); lsum += __shfl_xor(lsum, 32);
  float rb[4];
#pragma unroll
  for (int r = 0; r < 4; ++r)
    rb[r] = 1.0f / __shfl(lsum, quad * 4 + r, 16);
#pragma unroll
  for (int n = 0; n < 4; ++n) {
    int d = h * 64 + n * 16 + l15;
#pragma unroll
    for (int r = 0; r < 4; ++r) {
      int t = wrow + quad * 4 + r;
      yb[((size_t)b * T_ + t) * 1024 + d] = f2bf(acc[n][r] * rb[r]);
    }
  }
}

// ---------------- launch ----------------
extern "C" void kernel_launch(void* const* d_in, const int* in_sizes, int n_in,
                              void* d_out, int out_size, void* d_ws, size_t ws_size,
                              hipStream_t stream) {
  const float* x  = (const float*)d_in[0];
  const float* Wa = (const float*)d_in[1];
  const float* Wp = (const float*)d_in[2];
  float* out = (float*)d_out;
  char* ws = (char*)d_ws;

  // workspace layout (bytes), total 50,331,648
  u16*   xb    = (u16*)(ws + 0);           //  8,388,608  x bf16; reused as yb
  u16*   WaT   = (u16*)(ws + 8388608);     //  6,291,456  W_attn^T bf16
  u16*   WpT   = (u16*)(ws + 14680064);    //  2,097,152  W_proj^T bf16
  u16*   qkb   = (u16*)(ws + 16777216);    // 16,777,216  Q,K bf16 [2][32][2048][64]
  float* decR  = (float*)(ws + 33554432);  //      8,704  reversed padded decay table
  u16*   VT    = (u16*)(ws + 41943040);    //  8,388,608  V^T bf16 [32][64][2048]
  u16*   yb    = xb;

  decay_init_kernel<<<9, 256, 0, stream>>>(decR);
  cvt4_kernel<<<4096, 256, 0, stream>>>(x, xb, B_ * T_ * C_);
  transpose_cvt_kernel<<<dim3(96, 32), 256, 0, stream>>>(Wa, WaT, C_, N3_);
  transpose_cvt_kernel<<<dim3(32, 32), 256, 0, stream>>>(Wp, WpT, C_, C_);

  gemm128_kernel<0><<<768, 256, 0, stream>>>(
      xb, WaT, nullptr, qkb, VT, B_ * T_, N3_, C_);
  attn_kernel<<<1024, 256, 0, stream>>>(qkb, VT, decR, yb);
  gemm128_kernel<1><<<256, 256, 0, stream>>>(
      yb, WpT, out, nullptr, nullptr, B_ * T_, 1024, 1024);
}

// Round 10
// 104.499 us; speedup vs baseline: 1.1676x; 1.0916x over previous
//
#include <hip/hip_runtime.h>
#include <math.h>

// ws footprint: 50,331,648 bytes (decay table lives in the free region).
#define B_  2
#define T_  2048
#define C_  1024
#define NH_ 16
#define HD_ 64
#define N3_ 3072

typedef float f32x4 __attribute__((ext_vector_type(4)));
typedef short bf16x8 __attribute__((ext_vector_type(8)));
typedef unsigned short u16;
typedef float f32x4_base __attribute__((ext_vector_type(4)));
typedef f32x4_base __attribute__((aligned(4))) f32x4u;   // 4B-aligned vector load

// Q prescale: 1/sqrt(64) * log2(e), so softmax uses exp2 directly.
#define QSCALE 0.18033688011112042f

#if __has_builtin(__builtin_amdgcn_exp2f)
#define EXP2(x) __builtin_amdgcn_exp2f(x)
#else
#define EXP2(x) exp2f(x)
#endif

__device__ __forceinline__ u16 f2bf(float x) {
  unsigned int u = __builtin_bit_cast(unsigned int, x);
  u += 0x7FFFu + ((u >> 16) & 1u);
  return (u16)(u >> 16);
}

__device__ __forceinline__ unsigned int cvt_pk_bf16(float lo, float hi) {
  unsigned int r;
  asm("v_cvt_pk_bf16_f32 %0, %1, %2" : "=v"(r) : "v"(lo), "v"(hi));
  return r;
}

#define GLD16(g, l) __builtin_amdgcn_global_load_lds( \
    (__attribute__((address_space(1))) void*)(g), \
    (__attribute__((address_space(3))) void*)(l), 16, 0, 0)

// ---------------- fused prep: x->bf16, Wa^T, Wp^T, decay table ----------------
// grid 8209: [0,4096) cvt x; [4096,7168) Wa transpose; [7168,8192) Wp transpose;
// [8192,8209) reversed+padded decay table (4352 entries; j>2047 pad -> 1.0).
__global__ __launch_bounds__(256) void prep_kernel(
    const float* __restrict__ x, u16* __restrict__ xb,
    const float* __restrict__ Wa, u16* __restrict__ WaT,
    const float* __restrict__ Wp, u16* __restrict__ WpT,
    float* __restrict__ decR)
{
  __shared__ float tile[32][33];
  const int bid = blockIdx.x;
  const int tid = threadIdx.x;
  if (bid < 4096) {
    int i = (bid * 256 + tid) * 4;
    float4 v = *(const float4*)(x + i);
    ushort4 o;
    o.x = f2bf(v.x); o.y = f2bf(v.y); o.z = f2bf(v.z); o.w = f2bf(v.w);
    *(ushort4*)(xb + i) = o;
  } else if (bid < 8192) {
    const float* in; u16* out; int Cc, c0, r0;
    if (bid < 7168) {
      int t = bid - 4096;
      in = Wa; out = WaT; Cc = N3_;
      c0 = (t % 96) * 32; r0 = (t / 96) * 32;
    } else {
      int t = bid - 7168;
      in = Wp; out = WpT; Cc = C_;
      c0 = (t % 32) * 32; r0 = (t / 32) * 32;
    }
    int tx = tid & 31, ty = tid >> 5;
#pragma unroll
    for (int rr = ty; rr < 32; rr += 8)
      tile[rr][tx] = in[(size_t)(r0 + rr) * Cc + c0 + tx];
    __syncthreads();
#pragma unroll
    for (int rr = ty; rr < 32; rr += 8)
      out[(size_t)(c0 + rr) * 1024 + r0 + tx] = f2bf(tile[tx][rr]);
  } else {
    int j = (bid - 8192) * 256 + tid;
    if (j < 4352) {
      int d = 2047 - j;
      float v = 1.0f;
      if (d >= 15) v = 1.0f - powf((float)(d - 15) * (1.0f / 2032.0f), 0.36787944117144233f);
      decR[j] = v;
    }
  }
}

// ---------------- GEMM: C[M][N] = A[M][K] * Bt[N][K]^T ----------------
// 128x128 tile, 4 waves, BK=32, TRIPLE-buffered LDS, counted vmcnt (T4):
// stage lands 2 compute-phases ahead; no vmcnt(0) drain in steady state.
// XCD-chunk swizzled flat grid (grid % 8 == 0).
template<int MODE>
__global__ __launch_bounds__(256, 3) void gemm128_kernel(
    const u16* __restrict__ A, const u16* __restrict__ Bt,
    float* __restrict__ Cf, u16* __restrict__ Cq, u16* __restrict__ Vt,
    int M, int N, int K)
{
  __shared__ char lds[49152];   // 3 bufs x (A 8KB + Bt 8KB)
  const int lane = threadIdx.x & 63;
  const int wave = threadIdx.x >> 6;
  const int nxb = N >> 7;
  const int orig = blockIdx.x;
  const int cpx = (int)gridDim.x >> 3;
  const int wg = (orig & 7) * cpx + (orig >> 3);
  const int m0 = (wg / nxb) << 7;
  const int n0 = (wg % nxb) << 7;
  const int wm = wave >> 1, wn = wave & 1;

  f32x4 acc[4][4] = {};

#define GSTAGE(buf, k0)                                                          \
  {                                                                              \
    _Pragma("unroll")                                                            \
    for (int c = 0; c < 2; ++c) {                                                \
      int chunk = wave * 2048 + c * 1024;                                        \
      int row = (chunk >> 6) + (lane >> 2);                                      \
      int wb = ((lane & 3) << 4) ^ ((row & 3) << 4);                             \
      GLD16((const char*)(A  + (size_t)(m0 + row) * K + (k0)) + wb,              \
            lds + (buf) * 16384 + chunk);                                        \
      GLD16((const char*)(Bt + (size_t)(n0 + row) * K + (k0)) + wb,              \
            lds + (buf) * 16384 + 8192 + chunk);                                 \
    }                                                                            \
  }

  const int nk = K >> 5;
  GSTAGE(0, 0);
  GSTAGE(1, 32);
  __syncthreads();                 // one full drain in the prologue only

  for (int i = 0; i < nk; ++i) {
    // wait for OWN stage(i) (4 GLD16); stage(i+1) may stay in flight
    if (i + 1 < nk) asm volatile("s_waitcnt vmcnt(4)" ::: "memory");
    else            asm volatile("s_waitcnt vmcnt(0)" ::: "memory");
    __builtin_amdgcn_s_barrier();          // all waves' stage(i) landed
    __builtin_amdgcn_sched_barrier(0);     // rule 18: no hoisting above the wait
    if (i + 2 < nk) GSTAGE((i + 2) % 3, (i + 2) * 32);   // buf (i-1)%3: readers done

    const char* base = lds + (i % 3) * 16384;
    bf16x8 af[4], bfr[4];
#pragma unroll
    for (int m = 0; m < 4; ++m) {
      int row = wm * 64 + m * 16 + (lane & 15);
      int wb = ((lane >> 4) << 4) ^ ((row & 3) << 4);
      af[m] = *(const bf16x8*)(base + row * 64 + wb);
    }
#pragma unroll
    for (int n = 0; n < 4; ++n) {
      int row = wn * 64 + n * 16 + (lane & 15);
      int wb = ((lane >> 4) << 4) ^ ((row & 3) << 4);
      bfr[n] = *(const bf16x8*)(base + 8192 + row * 64 + wb);
    }
    __builtin_amdgcn_s_setprio(1);
#pragma unroll
    for (int m = 0; m < 4; ++m)
#pragma unroll
      for (int n = 0; n < 4; ++n)
        acc[m][n] = __builtin_amdgcn_mfma_f32_16x16x32_bf16(af[m], bfr[n], acc[m][n], 0, 0, 0);
    __builtin_amdgcn_s_setprio(0);
    // no end-of-iter barrier: next iteration's wait+barrier provides the sync
  }

#pragma unroll
  for (int m = 0; m < 4; ++m) {
    int grow0 = m0 + wm * 64 + m * 16 + ((lane >> 4) << 2);
#pragma unroll
    for (int n = 0; n < 4; ++n) {
      int gcol = n0 + wn * 64 + n * 16 + (lane & 15);
      f32x4 v = acc[m][n];
      if (MODE == 0) {
        int bb = grow0 >> 11, tt0 = grow0 & 2047;
        int which = gcol >> 10, rem = gcol & 1023;
        int hh = rem >> 6, dd = rem & 63;
        if (which < 2) {
#pragma unroll
          for (int r = 0; r < 4; ++r) {
            float ov = (which == 0) ? v[r] * QSCALE : v[r];
            Cq[((size_t)(which * 32 + bb * 16 + hh) * 2048 + tt0 + r) * 64 + dd] = f2bf(ov);
          }
        } else {
          ushort4 o;
          o.x = f2bf(v[0]); o.y = f2bf(v[1]); o.z = f2bf(v[2]); o.w = f2bf(v[3]);
          *(ushort4*)(Vt + ((size_t)(bb * 16 + hh) * 64 + dd) * 2048 + tt0) = o;
        }
      } else {
#pragma unroll
        for (int r = 0; r < 4; ++r)
          Cf[(size_t)(grow0 + r) * N + gcol] = v[r];
      }
    }
  }
#undef GSTAGE
}

// ---------------- fused flash attention with post-softmax decay ----------------
// flat grid 512; block = PAIRED q-tiles (qtA short, qtB=31-qtA long): one K/V
// stage serves both tiles (halves L2 stage traffic). Counted vmcnt (T4): the
// loop never drains vmcnt(0) -- wait vmcnt(8) -> s_barrier -> stage(next).
// Decay factors prefetched one iter ahead (always 8 loads -> static count).
// CU-mates (orig, orig+256) get complementary qtA (sum 15) and same bh:
// 49 stage-iters per CU, uniform. S^T = mfma(K,Q): keys lane-local.
__global__ __launch_bounds__(256, 2) void attn_kernel(
    const u16* __restrict__ qkb, const u16* __restrict__ vtg,
    const float* __restrict__ decR, u16* __restrict__ yb)
{
  __shared__ char klds[2][8192];   // K tile [64 keys][128B], XOR-swizzled
  __shared__ char vlds[2][8192];   // V^T tile [64 d][128B keys], XOR-swizzled
  __shared__ u16 plds[128 * 76];   // P [q][key]: rows 0..63 tile B, 64..127 tile A

  const int lane = threadIdx.x & 63;
  const int wave = threadIdx.x >> 6;
  const int quad = lane >> 4;
  const int l15 = lane & 15;
  const int orig = blockIdx.x;
  const int xcd = orig & 7;
  const int j = orig >> 3;             // 0..63 within XCD
  const int bh = xcd * 4 + (j & 3);    // CU-mates (j, j+32): same bh
  const int tt = j >> 2;               // 0..15; CU-mates tt, tt+8
  const int qtA = (tt < 8) ? tt : 23 - tt;   // complementary: qtA(tt)+qtA(tt+8)=15
  const int qtB = 31 - qtA;
  const int b = bh >> 4, h = bh & 15;

  const u16* Q   = qkb + (size_t)bh * T_ * HD_;
  const u16* Kg  = qkb + (size_t)(32 + bh) * T_ * HD_;
  const u16* VTg = vtg + (size_t)bh * HD_ * T_;

  const int wrowB = qtB * 64 + wave * 16;
  const int wrowA = qtA * 64 + wave * 16;
  const int qB = wrowB + l15;
  const int qA = wrowA + l15;
  const float* dpB = decR + (2047 - qB + quad * 4);
  const float* dpA = decR + (2047 - qA + quad * 4);

  bf16x8 qaB[2], qaA[2];
  { const u16* qp = Q + (size_t)qB * HD_ + quad * 8;
    qaB[0] = *(const bf16x8*)qp; qaB[1] = *(const bf16x8*)(qp + 32); }
  { const u16* qp = Q + (size_t)qA * HD_ + quad * 8;
    qaA[0] = *(const bf16x8*)qp; qaA[1] = *(const bf16x8*)(qp + 32); }

  f32x4 accB[4] = {}, accA[4] = {};
  float lsumB = 0.0f, lsumA = 0.0f;

#define ASTAGE(buf, kt)                                                          \
  {                                                                              \
    _Pragma("unroll")                                                            \
    for (int c = 0; c < 2; ++c) {                                                \
      int chunk = wave * 2048 + c * 1024;                                        \
      int row = (chunk >> 7) + (lane >> 3);                                      \
      int wb = ((lane & 7) << 4) ^ ((row & 7) << 4);                             \
      GLD16((const char*)(Kg + (size_t)((kt) * 64 + row) * HD_) + wb,            \
            klds[buf] + chunk);                                                  \
      GLD16((const char*)(VTg + (size_t)row * T_ + (kt) * 64) + wb,              \
            vlds[buf] + chunk);                                                  \
    }                                                                            \
  }

  // prologue: decay(0) prefetch + stage(0), then ONE full drain
  f32x4 dBc[4], dAc[4], dBn[4], dAn[4];
#pragma unroll
  for (int f = 0; f < 4; ++f) {
    dBn[f] = *(const f32x4u*)(dpB + f * 16);
    dAn[f] = *(const f32x4u*)(dpA + f * 16);
  }
  ASTAGE(0, 0);
  __syncthreads();

  const int nkt = qtB + 1;
  for (int kt = 0; kt < nkt; ++kt) {
    const int cur = kt & 1;
    // rotate decay regs; prefetch decay(kt+1) (ALWAYS 8 loads -> static vmcnt;
    // table padded to 4352 entries so kt+1==nkt reads are in-bounds)
#pragma unroll
    for (int f = 0; f < 4; ++f) { dBc[f] = dBn[f]; dAc[f] = dAn[f]; }
    const float* dB1 = dpB + (kt + 1) * 64;
    const float* dA1 = dpA + (kt + 1) * 64;
#pragma unroll
    for (int f = 0; f < 4; ++f) {
      dBn[f] = *(const f32x4u*)(dB1 + f * 16);
      dAn[f] = *(const f32x4u*)(dA1 + f * 16);
    }
    // counted wait: retires stage(kt) + decay(kt); leaves decay(kt+1) in flight
    asm volatile("s_waitcnt vmcnt(8)" ::: "memory");
    __builtin_amdgcn_s_barrier();
    __builtin_amdgcn_sched_barrier(0);
    if (kt + 1 < nkt) ASTAGE(cur ^ 1, kt + 1);   // buf readers done (barrier)

    const bool actA = (kt <= qtA);

    // K fragments (read once, shared by both q-tiles)
    bf16x8 kf[4][2];
#pragma unroll
    for (int f = 0; f < 4; ++f) {
      int krow = f * 16 + l15;
      int base = krow * 128;
      int msk = (krow & 7) << 4;
      kf[f][0] = *(const bf16x8*)(klds[cur] + base + ((quad * 16) ^ msk));
      kf[f][1] = *(const bf16x8*)(klds[cur] + base + ((64 + quad * 16) ^ msk));
    }

    // S^T = K Q^T (log2 domain): col=q=l15, row=key=f*16+quad*4+r
    f32x4 sB[4], sA[4];
    __builtin_amdgcn_s_setprio(1);
#pragma unroll
    for (int f = 0; f < 4; ++f) {
      f32x4 t = {};
      t = __builtin_amdgcn_mfma_f32_16x16x32_bf16(kf[f][0], qaB[0], t, 0, 0, 0);
      t = __builtin_amdgcn_mfma_f32_16x16x32_bf16(kf[f][1], qaB[1], t, 0, 0, 0);
      sB[f] = t;
    }
    if (actA) {
#pragma unroll
      for (int f = 0; f < 4; ++f) {
        f32x4 t = {};
        t = __builtin_amdgcn_mfma_f32_16x16x32_bf16(kf[f][0], qaA[0], t, 0, 0, 0);
        t = __builtin_amdgcn_mfma_f32_16x16x32_bf16(kf[f][1], qaA[1], t, 0, 0, 0);
        sA[f] = t;
      }
    }
    __builtin_amdgcn_s_setprio(0);

    if (kt == qtB) {   // diagonal: mask key > q
#pragma unroll
      for (int f = 0; f < 4; ++f) {
        int key0 = kt * 64 + f * 16 + quad * 4;
#pragma unroll
        for (int r = 0; r < 4; ++r)
          if (key0 + r > qB) sB[f][r] = -1e30f;
      }
    }
    if (actA && kt == qtA) {
#pragma unroll
      for (int f = 0; f < 4; ++f) {
        int key0 = kt * 64 + f * 16 + quad * 4;
#pragma unroll
        for (int r = 0; r < 4; ++r)
          if (key0 + r > qA) sA[f][r] = -1e30f;
      }
    }

    // softmax: denom = sum exp2(s); numerator = exp2(s)*decay -> packed bf16
#pragma unroll
    for (int f = 0; f < 4; ++f) {
      f32x4 p;
#pragma unroll
      for (int r = 0; r < 4; ++r) p[r] = EXP2(sB[f][r]);
      lsumB += (p[0] + p[1]) + (p[2] + p[3]);
      unsigned int w0 = cvt_pk_bf16(p[0] * dBc[f][0], p[1] * dBc[f][1]);
      unsigned int w1 = cvt_pk_bf16(p[2] * dBc[f][2], p[3] * dBc[f][3]);
      uint2 wv; wv.x = w0; wv.y = w1;
      *(uint2*)(plds + (size_t)(wave * 16 + l15) * 76 + f * 16 + quad * 4) = wv;
    }
    if (actA) {
#pragma unroll
      for (int f = 0; f < 4; ++f) {
        f32x4 p;
#pragma unroll
        for (int r = 0; r < 4; ++r) p[r] = EXP2(sA[f][r]);
        lsumA += (p[0] + p[1]) + (p[2] + p[3]);
        unsigned int w0 = cvt_pk_bf16(p[0] * dAc[f][0], p[1] * dAc[f][1]);
        unsigned int w1 = cvt_pk_bf16(p[2] * dAc[f][2], p[3] * dAc[f][3]);
        uint2 wv; wv.x = w0; wv.y = w1;
        *(uint2*)(plds + (size_t)(64 + wave * 16 + l15) * 76 + f * 16 + quad * 4) = wv;
      }
    }

    // V fragments (read once, shared)
    bf16x8 vf[4][2];
#pragma unroll
    for (int n = 0; n < 4; ++n) {
      int vrow = n * 16 + l15;
      int mskv = (vrow & 7) << 4;
#pragma unroll
      for (int ks = 0; ks < 2; ++ks)
        vf[n][ks] = *(const bf16x8*)(vlds[cur] + vrow * 128 + ((ks * 64 + quad * 16) ^ mskv));
    }

    // y += P @ V (plds rows are wave-private)
    __builtin_amdgcn_s_setprio(1);
#pragma unroll
    for (int ks = 0; ks < 2; ++ks) {
      bf16x8 pa = *(const bf16x8*)(plds + (size_t)(wave * 16 + l15) * 76 + ks * 32 + quad * 8);
#pragma unroll
      for (int n = 0; n < 4; ++n)
        accB[n] = __builtin_amdgcn_mfma_f32_16x16x32_bf16(pa, vf[n][ks], accB[n], 0, 0, 0);
    }
    if (actA) {
#pragma unroll
      for (int ks = 0; ks < 2; ++ks) {
        bf16x8 pa = *(const bf16x8*)(plds + (size_t)(64 + wave * 16 + l15) * 76 + ks * 32 + quad * 8);
#pragma unroll
        for (int n = 0; n < 4; ++n)
          accA[n] = __builtin_amdgcn_mfma_f32_16x16x32_bf16(pa, vf[n][ks], accA[n], 0, 0, 0);
      }
    }
    __builtin_amdgcn_s_setprio(0);
    // no end-of-iter barrier: next iteration's wait+barrier provides the sync
  }
#undef ASTAGE

  // finalize: denom for q=l15 -> reduce across quads, broadcast to q=quad*4+r
  lsumB += __shfl_xor(lsumB, 16); lsumB += __shfl_xor(lsumB, 32);
  lsumA += __shfl_xor(lsumA, 16); lsumA += __shfl_xor(lsumA, 32);
  float rB[4], rA[4];
#pragma unroll
  for (int r = 0; r < 4; ++r) {
    rB[r] = 1.0f / __shfl(lsumB, quad * 4 + r, 16);
    rA[r] = 1.0f / __shfl(lsumA, quad * 4 + r, 16);
  }
#pragma unroll
  for (int n = 0; n < 4; ++n) {
    int d = h * 64 + n * 16 + l15;
#pragma unroll
    for (int r = 0; r < 4; ++r) {
      int tB = wrowB + quad * 4 + r;
      int tA = wrowA + quad * 4 + r;
      yb[((size_t)b * T_ + tB) * 1024 + d] = f2bf(accB[n][r] * rB[r]);
      yb[((size_t)b * T_ + tA) * 1024 + d] = f2bf(accA[n][r] * rA[r]);
    }
  }
}

// ---------------- launch ----------------
extern "C" void kernel_launch(void* const* d_in, const int* in_sizes, int n_in,
                              void* d_out, int out_size, void* d_ws, size_t ws_size,
                              hipStream_t stream) {
  const float* x  = (const float*)d_in[0];
  const float* Wa = (const float*)d_in[1];
  const float* Wp = (const float*)d_in[2];
  float* out = (float*)d_out;
  char* ws = (char*)d_ws;

  // workspace layout (bytes), total 50,331,648
  u16*   xb    = (u16*)(ws + 0);           //  8,388,608  x bf16; reused as yb
  u16*   WaT   = (u16*)(ws + 8388608);     //  6,291,456  W_attn^T bf16
  u16*   WpT   = (u16*)(ws + 14680064);    //  2,097,152  W_proj^T bf16
  u16*   qkb   = (u16*)(ws + 16777216);    // 16,777,216  Q,K bf16 [2][32][2048][64]
  float* decR  = (float*)(ws + 33554432);  //     17,408  reversed padded decay (4352)
  u16*   VT    = (u16*)(ws + 41943040);    //  8,388,608  V^T bf16 [32][64][2048]
  u16*   yb    = xb;

  prep_kernel<<<8209, 256, 0, stream>>>(x, xb, Wa, WaT, Wp, WpT, decR);
  gemm128_kernel<0><<<768, 256, 0, stream>>>(
      xb, WaT, nullptr, qkb, VT, B_ * T_, N3_, C_);
  attn_kernel<<<512, 256, 0, stream>>>(qkb, VT, decR, yb);
  gemm128_kernel<1><<<256, 256, 0, stream>>>(
      yb, WpT, out, nullptr, nullptr, B_ * T_, 1024, 1024);
}